// Round 13
// baseline (56.088 us; speedup 1.0000x reference)
//
#include <hip/hip_runtime.h>

// UVFA_text r13: single main kernel (r10 structure) + full f16 weight packing.
// pack (streams f32 masters -> f16 tables, lands them in L3):
//   WhhT[512][128], WihT[512][64], Ws2P u32-pairs, Wo1h, Ws1h, Wo2h, Wo3h, Ws3h
// main: all weight reads are f16 from the packed (L3-hot) tables.
// LSTM: r12's validated in-lane form (waves 0-7, 1 barrier/step, pinned A-frags).

#define B_   256
#define M2_  100
#define R_   128
#define L_   12
#define E_   64
#define NT   1024

typedef _Float16 half2v __attribute__((ext_vector_type(2)));
typedef _Float16 f16x8  __attribute__((ext_vector_type(8)));
typedef float    f32x4  __attribute__((ext_vector_type(4)));

__device__ __forceinline__ float sigf(float x) { return 1.f / (1.f + expf(-x)); }

__device__ __forceinline__ uint pk16(float a, float b) {
    half2v h; h.x = (_Float16)a; h.y = (_Float16)b;
    return __builtin_bit_cast(uint, h);
}

#define PINU4(v) asm volatile("" : "+v"(v.x), "+v"(v.y), "+v"(v.z), "+v"(v.w));

// ---------------- pack: all weights -> f16 (coalesced streaming) ----------------
// items: 65536 WhhT | 32768 WihT | 8192 W2P | 409600 Wo1h | 422400 Ws1h
//        | 16384 Wo2h | 16384 Wo3h | 16384 Ws3h   (total 987648)
__global__ __launch_bounds__(256) void pack_kernel(
    const float* __restrict__ Whh, const float* __restrict__ Wih,
    const float* __restrict__ Ws2, const float* __restrict__ Wo1,
    const float* __restrict__ Ws1, const float* __restrict__ Wo2,
    const float* __restrict__ Wo3, const float* __restrict__ Ws3,
    void* __restrict__ wsv)
{
    _Float16* WhhT = (_Float16*)wsv;
    _Float16* WihT = WhhT + 65536;
    uint*     W2P  = (uint*)(WihT + 32768);
    _Float16* Wo1h = (_Float16*)(W2P + 8192);
    _Float16* Ws1h = Wo1h + 409600;
    _Float16* Wo2h = Ws1h + 422400;
    _Float16* Wo3h = Wo2h + 16384;
    _Float16* Ws3h = Wo3h + 16384;
    int g = blockIdx.x * 256 + threadIdx.x;
    if (g < 65536) {
        int r = g >> 9, c = g & 511;
        WhhT[c * 128 + r] = (_Float16)Whh[g];
    } else if (g < 98304) {
        int g2 = g - 65536; int e = g2 >> 9, c = g2 & 511;
        WihT[c * 64 + e] = (_Float16)Wih[g2];
    } else if (g < 106496) {
        int g3 = g - 98304; int jp = g3 >> 7, kk = g3 & 127;
        W2P[g3] = pk16(Ws2[(2 * jp) * R_ + kk], Ws2[(2 * jp + 1) * R_ + kk]);
    } else if (g < 516096) {
        int i = g - 106496; Wo1h[i] = (_Float16)Wo1[i];
    } else if (g < 938496) {
        int i = g - 516096; Ws1h[i] = (_Float16)Ws1[i];
    } else if (g < 954880) {
        int i = g - 938496; Wo2h[i] = (_Float16)Wo2[i];
    } else if (g < 971264) {
        int i = g - 954880; Wo3h[i] = (_Float16)Wo3[i];
    } else if (g < 987648) {
        int i = g - 971264; Ws3h[i] = (_Float16)Ws3[i];
    }
}

__global__ __launch_bounds__(NT) __attribute__((amdgpu_waves_per_eu(4, 4)))
void uvfa_kernel(
    const int* __restrict__ state, const int* __restrict__ obj, const int* __restrict__ text,
    const float* __restrict__ bs1, const float* __restrict__ bs2, const float* __restrict__ bs3,
    const float* __restrict__ bo1, const float* __restrict__ bo2, const float* __restrict__ bo3,
    const float* __restrict__ emb, const float* __restrict__ b_lstm,
    const _Float16* __restrict__ WhhT, const _Float16* __restrict__ WihT,
    const uint* __restrict__ W2P,
    const _Float16* __restrict__ Wo1h, const _Float16* __restrict__ Ws1h,
    const _Float16* __restrict__ Wo2h, const _Float16* __restrict__ Wo3h,
    const _Float16* __restrict__ Ws3h,
    float* __restrict__ out)
{
    const int b   = blockIdx.x;
    const int tid = threadIdx.x;

    // U: phase A = xw f32 [12][512] (0..6143) + xemb f32 [16][66] (8192..9247)
    //    phase B = Ws2P u32 [64][132] (0..8447) + h1P u32 [112][68] (8448..16063)
    __shared__ __align__(16) uint  U[16064];
    __shared__ __align__(16) float part[NT];
    __shared__ __align__(16) float hbuf[R_];
    __shared__ __align__(16) uint  hpair[2][64];
    __shared__ __align__(16) float tmp[R_], tmp2[R_], wbuf[R_], ubuf[R_], bsbuf[R_];
    __shared__ float redw2[2][112];
    __shared__ int   idx_o[M2_], idx_s[M2_], tids[L_];
    __shared__ float c0s;

    float* xw   = (float*)U;            // [12][512]
    float* xemb = (float*)(U + 8192);   // [16][66], rows 12..15 zero

    const int lane = tid & 63;
    const int wv   = tid >> 6;          // 0..15
    const int m16  = lane & 15;
    const int kgrp = lane >> 4;         // 0..3
    const int k = tid & 127, qq = tid >> 7;   // qq 0..7

    // ---------- LSTM A-fragments (waves 0..7): 64 VGPRs, pinned ----------
    uint4 afu[4][4];
    if (wv < 8) {
        #pragma unroll
        for (int g = 0; g < 4; ++g) {
            int col = (wv + 8 * g) * 16 + m16;
            #pragma unroll
            for (int s = 0; s < 4; ++s) {
                afu[g][s] = *(const uint4*)&WhhT[col * 128 + s * 32 + kgrp * 8];
                PINU4(afu[g][s])
            }
        }
    }

    // ---------- P1: ids + init ----------
    if (tid < M2_) idx_o[tid] = obj[b * M2_ + tid];
    else if (tid >= 128 && tid < 128 + M2_) idx_s[tid - 128] = state[b * M2_ + tid - 128];
    else if (tid >= 256 && tid < 256 + L_) tids[tid - 256] = text[b * L_ + tid - 256];
    else if (tid >= 384 && tid < 448) hpair[0][tid - 384] = 0u;
    __syncthreads();
    if (tid < L_ * E_) xemb[(tid >> 6) * 66 + (tid & 63)] = emb[tids[tid >> 6] * E_ + (tid & 63)];
    else if (tid < L_ * E_ + 264) ((float*)(U + 8192 + 792))[tid - L_ * E_] = 0.f;
    __syncthreads();

    // ---------- P2: xw = b_lstm + x @ Wih via MFMA (16 waves x 2 cols) ----------
    {
        f16x8 ax[2];
        #pragma unroll
        for (int s = 0; s < 2; ++s)
            #pragma unroll
            for (int e = 0; e < 8; ++e)
                ax[s][e] = (_Float16)xemb[m16 * 66 + s * 32 + kgrp * 8 + e];
        #pragma unroll
        for (int h = 0; h < 2; ++h) {
            int col = (wv * 2 + h) * 16 + m16;
            float bl = b_lstm[col];
            f32x4 acc = { bl, bl, bl, bl };
            #pragma unroll
            for (int s = 0; s < 2; ++s) {
                f16x8 bx = *(const f16x8*)&WihT[col * 64 + s * 32 + kgrp * 8];
                acc = __builtin_amdgcn_mfma_f32_16x16x32_f16(ax[s], bx, acc, 0, 0, 0);
            }
            if (kgrp < 3) {
                #pragma unroll
                for (int r = 0; r < 4; ++r)
                    xw[(kgrp * 4 + r) * 512 + col] = acc[r];
            }
        }
    }
    __syncthreads();

    // ---------- LSTM: 12 steps, in-lane nonlinearity (r12-validated), 1 barrier ----
    float cst0 = 0.f, cst1 = 0.f, cst2 = 0.f, cst3 = 0.f;
    float h0 = 0.f, h1v = 0.f, h2v = 0.f, h3v = 0.f;
    for (int t = 0; t < L_; ++t) {
        if (wv < 8) {
            const uint* hp = hpair[t & 1];
            f16x8 bf[4];
            #pragma unroll
            for (int s = 0; s < 4; ++s)
                bf[s] = __builtin_bit_cast(f16x8, *(const uint4*)&hp[s * 16 + kgrp * 4]);
            f32x4 acc[4];
            #pragma unroll
            for (int g = 0; g < 4; ++g) {
                acc[g] = *(const f32x4*)&xw[t * 512 + (wv + 8 * g) * 16 + kgrp * 4];
                #pragma unroll
                for (int s = 0; s < 4; ++s)
                    acc[g] = __builtin_amdgcn_mfma_f32_16x16x32_f16(
                        __builtin_bit_cast(f16x8, afu[g][s]), bf[s], acc[g], 0, 0, 0);
            }
            cst0 = sigf(acc[1][0]) * cst0 + sigf(acc[0][0]) * tanhf(acc[2][0]);
            h0   = sigf(acc[3][0]) * tanhf(cst0);
            cst1 = sigf(acc[1][1]) * cst1 + sigf(acc[0][1]) * tanhf(acc[2][1]);
            h1v  = sigf(acc[3][1]) * tanhf(cst1);
            cst2 = sigf(acc[1][2]) * cst2 + sigf(acc[0][2]) * tanhf(acc[2][2]);
            h2v  = sigf(acc[3][2]) * tanhf(cst2);
            cst3 = sigf(acc[1][3]) * cst3 + sigf(acc[0][3]) * tanhf(acc[2][3]);
            h3v  = sigf(acc[3][3]) * tanhf(cst3);
            if (m16 == 0) {
                uint* hw = hpair[(t + 1) & 1];
                hw[8 * wv + kgrp * 2]     = pk16(h0, h1v);
                hw[8 * wv + kgrp * 2 + 1] = pk16(h2v, h3v);
            }
        }
        __syncthreads();
    }
    if (wv < 8 && m16 == 0) {
        int j = wv * 16 + kgrp * 4;
        hbuf[j + 0] = h0;
        hbuf[j + 1] = h1v;
        hbuf[j + 2] = h2v;
        hbuf[j + 3] = h3v;
    }

    // ---------- stage Ws2P [64][132] via uint4 copy (xw dead) ----------
    {
        const uint4* src = (const uint4*)W2P;
        #pragma unroll
        for (int idx = tid; idx < 2048; idx += NT) {
            uint4 v = src[idx];
            int jp = idx >> 5, kq = idx & 31;
            *(uint4*)&U[jp * 132 + kq * 4] = v;
        }
    }

    // ---------- P4: object MLP (f16 tables) ----------
    {
        float acc = 0.f;
        int c0i = qq * 13, c1i = c0i + 13 < M2_ ? c0i + 13 : M2_;
        for (int c = c0i; c < c1i; ++c)
            acc += (float)Wo1h[(c * 32 + idx_o[c]) * R_ + k];
        part[qq * R_ + k] = acc;
    }
    __syncthreads();
    if (tid < R_) {
        float a = bo1[tid];
        #pragma unroll
        for (int q8 = 0; q8 < 8; ++q8) a += part[q8 * R_ + tid];
        tmp[tid] = fmaxf(a, 0.f);
    }
    __syncthreads();
    {
        float s0 = 0.f, s1 = 0.f, s2 = 0.f, s3 = 0.f;
        int j0 = qq * 16;
        #pragma unroll
        for (int j = 0; j < 16; j += 4) {
            s0 = fmaf(tmp[j0 + j + 0], (float)Wo2h[(j0 + j + 0) * R_ + k], s0);
            s1 = fmaf(tmp[j0 + j + 1], (float)Wo2h[(j0 + j + 1) * R_ + k], s1);
            s2 = fmaf(tmp[j0 + j + 2], (float)Wo2h[(j0 + j + 2) * R_ + k], s2);
            s3 = fmaf(tmp[j0 + j + 3], (float)Wo2h[(j0 + j + 3) * R_ + k], s3);
        }
        part[qq * R_ + k] = (s0 + s1) + (s2 + s3);
    }
    __syncthreads();
    if (tid < R_) {
        float a = bo2[tid];
        #pragma unroll
        for (int q8 = 0; q8 < 8; ++q8) a += part[q8 * R_ + tid];
        tmp2[tid] = fmaxf(a, 0.f);
    }
    __syncthreads();
    {
        float s0 = 0.f, s1 = 0.f, s2 = 0.f, s3 = 0.f;
        int j0 = qq * 16;
        #pragma unroll
        for (int j = 0; j < 16; j += 4) {
            s0 = fmaf(tmp2[j0 + j + 0], (float)Wo3h[(j0 + j + 0) * R_ + k], s0);
            s1 = fmaf(tmp2[j0 + j + 1], (float)Wo3h[(j0 + j + 1) * R_ + k], s1);
            s2 = fmaf(tmp2[j0 + j + 2], (float)Wo3h[(j0 + j + 2) * R_ + k], s2);
            s3 = fmaf(tmp2[j0 + j + 3], (float)Wo3h[(j0 + j + 3) * R_ + k], s3);
        }
        part[qq * R_ + k] = (s0 + s1) + (s2 + s3);
    }
    __syncthreads();
    if (tid < R_) {
        float a = bo3[tid];
        #pragma unroll
        for (int q8 = 0; q8 < 8; ++q8) a += part[q8 * R_ + tid];
        wbuf[tid] = a * hbuf[tid];
    }
    __syncthreads();

    // ---------- P5: u = Ws3 @ w ; c0 = bs3 . w (Ws3h f16) ----------
    {
        float s0 = 0.f, s1 = 0.f, s2 = 0.f, s3 = 0.f;
        int j0 = qq * 16;
        f16x8 va = *(const f16x8*)&Ws3h[k * R_ + j0];
        f16x8 vb = *(const f16x8*)&Ws3h[k * R_ + j0 + 8];
        #pragma unroll
        for (int e = 0; e < 8; e += 4) {
            s0 = fmaf((float)va[e + 0], wbuf[j0 + e + 0], s0);
            s1 = fmaf((float)va[e + 1], wbuf[j0 + e + 1], s1);
            s2 = fmaf((float)va[e + 2], wbuf[j0 + e + 2], s2);
            s3 = fmaf((float)va[e + 3], wbuf[j0 + e + 3], s3);
        }
        #pragma unroll
        for (int e = 0; e < 8; e += 4) {
            s0 = fmaf((float)vb[e + 0], wbuf[j0 + 8 + e + 0], s0);
            s1 = fmaf((float)vb[e + 1], wbuf[j0 + 8 + e + 1], s1);
            s2 = fmaf((float)vb[e + 2], wbuf[j0 + 8 + e + 2], s2);
            s3 = fmaf((float)vb[e + 3], wbuf[j0 + 8 + e + 3], s3);
        }
        part[qq * R_ + k] = (s0 + s1) + (s2 + s3);
    }
    if (tid >= 960) {
        int j = tid - 960;
        float s = bs3[j] * wbuf[j] + bs3[j + 64] * wbuf[j + 64];
        s += __shfl_down(s, 32, 64);
        s += __shfl_down(s, 16, 64);
        s += __shfl_down(s, 8, 64);
        s += __shfl_down(s, 4, 64);
        s += __shfl_down(s, 2, 64);
        s += __shfl_down(s, 1, 64);
        if (j == 0) c0s = s;
    }
    __syncthreads();
    if (tid < R_) {
        float a = 0.f;
        #pragma unroll
        for (int q8 = 0; q8 < 8; ++q8) a += part[q8 * R_ + tid];
        ubuf[tid] = a;
    }
    __syncthreads();

    // ---------- P6: base_s gather (Ws1h f16) ----------
    {
        float acc = 0.f;
        int c0i = qq * 13, c1i = c0i + 13 < M2_ ? c0i + 13 : M2_;
        for (int c = c0i; c < c1i; ++c)
            acc += (float)Ws1h[(c * 33 + idx_s[c]) * R_ + k];
        part[qq * R_ + k] = acc;
    }
    __syncthreads();
    if (tid < R_) {
        float a = bs1[tid];
        #pragma unroll
        for (int q8 = 0; q8 < 8; ++q8) a += part[q8 * R_ + tid];
        bsbuf[tid] = a;
    }
    __syncthreads();

    // ---------- stage h1P [112][68] f16-pairs; zero rows 100..111 ----------
    #pragma unroll 4
    for (int pass = 0; pass < 13; ++pass) {
        int idx = pass * NT + tid;
        if (idx < M2_ * R_) {
            int j = idx & 127, p = idx >> 7;
            float v = fmaxf(bsbuf[j] + (float)Ws1h[(p * 33 + 32) * R_ + j], 0.f);
            float v2 = __shfl_down(v, 1, 64);
            if (!(j & 1)) U[8448 + p * 68 + (j >> 1)] = pk16(v, v2);
        }
    }
    if (tid < 816) U[8448 + 6800 + tid] = 0u;
    __syncthreads();

    // ---------- P8: h2 = h1 @ Ws2 via MFMA; wave = (mtile, nhalf) ----------
    if (wv < 14) {
        const int mtile = wv >> 1, nhalf = wv & 1;
        const uint* Ap = U + 8448 + (mtile * 16 + m16) * 68;
        f16x8 A[4];
        #pragma unroll
        for (int s = 0; s < 4; ++s)
            A[s] = __builtin_bit_cast(f16x8, *(const uint4*)&Ap[s * 16 + kgrp * 4]);
        f32x4 acc[4] = { {0,0,0,0}, {0,0,0,0}, {0,0,0,0}, {0,0,0,0} };
        #pragma unroll
        for (int nt = 0; nt < 4; ++nt) {
            int ko = (nhalf * 4 + nt) * 16 + m16;
            #pragma unroll
            for (int s = 0; s < 4; ++s) {
                const uint* Bp = U + (s * 16 + kgrp * 4) * 132 + ko;
                uint4 bv = { Bp[0], Bp[132], Bp[264], Bp[396] };
                acc[nt] = __builtin_amdgcn_mfma_f32_16x16x32_f16(
                    A[s], __builtin_bit_cast(f16x8, bv), acc[nt], 0, 0, 0);
            }
        }
        float vs0 = 0.f, vs1 = 0.f, vs2 = 0.f, vs3 = 0.f;
        #pragma unroll
        for (int nt = 0; nt < 4; ++nt) {
            int ko = (nhalf * 4 + nt) * 16 + m16;
            float bb = bs2[ko], uu = ubuf[ko];
            vs0 = fmaf(fmaxf(acc[nt][0] + bb, 0.f), uu, vs0);
            vs1 = fmaf(fmaxf(acc[nt][1] + bb, 0.f), uu, vs1);
            vs2 = fmaf(fmaxf(acc[nt][2] + bb, 0.f), uu, vs2);
            vs3 = fmaf(fmaxf(acc[nt][3] + bb, 0.f), uu, vs3);
        }
        vs0 += __shfl_xor(vs0, 1, 64); vs0 += __shfl_xor(vs0, 2, 64);
        vs0 += __shfl_xor(vs0, 4, 64); vs0 += __shfl_xor(vs0, 8, 64);
        vs1 += __shfl_xor(vs1, 1, 64); vs1 += __shfl_xor(vs1, 2, 64);
        vs1 += __shfl_xor(vs1, 4, 64); vs1 += __shfl_xor(vs1, 8, 64);
        vs2 += __shfl_xor(vs2, 1, 64); vs2 += __shfl_xor(vs2, 2, 64);
        vs2 += __shfl_xor(vs2, 4, 64); vs2 += __shfl_xor(vs2, 8, 64);
        vs3 += __shfl_xor(vs3, 1, 64); vs3 += __shfl_xor(vs3, 2, 64);
        vs3 += __shfl_xor(vs3, 4, 64); vs3 += __shfl_xor(vs3, 8, 64);
        if (m16 == 0) {
            int pr = mtile * 16 + kgrp * 4;
            redw2[nhalf][pr + 0] = vs0;
            redw2[nhalf][pr + 1] = vs1;
            redw2[nhalf][pr + 2] = vs2;
            redw2[nhalf][pr + 3] = vs3;
        }
    }
    __syncthreads();

    if (tid < M2_)
        out[b * M2_ + tid] = c0s + redw2[0][tid] + redw2[1][tid];
}

extern "C" void kernel_launch(void* const* d_in, const int* in_sizes, int n_in,
                              void* d_out, int out_size, void* d_ws, size_t ws_size,
                              hipStream_t stream) {
    const int*   state  = (const int*)d_in[0];
    const int*   obj    = (const int*)d_in[1];
    const int*   text   = (const int*)d_in[2];
    const float* Ws1    = (const float*)d_in[3];
    const float* bs1    = (const float*)d_in[4];
    const float* Ws2    = (const float*)d_in[5];
    const float* bs2    = (const float*)d_in[6];
    const float* Ws3    = (const float*)d_in[7];
    const float* bs3    = (const float*)d_in[8];
    const float* Wo1    = (const float*)d_in[9];
    const float* bo1    = (const float*)d_in[10];
    const float* Wo2    = (const float*)d_in[11];
    const float* bo2    = (const float*)d_in[12];
    const float* Wo3    = (const float*)d_in[13];
    const float* bo3    = (const float*)d_in[14];
    const float* emb    = (const float*)d_in[15];
    const float* Wih    = (const float*)d_in[16];
    const float* Whh    = (const float*)d_in[17];
    const float* b_lstm = (const float*)d_in[18];
    float* out = (float*)d_out;

    _Float16* WhhT = (_Float16*)d_ws;
    _Float16* WihT = WhhT + 65536;
    uint*     W2P  = (uint*)(WihT + 32768);
    _Float16* Wo1h = (_Float16*)(W2P + 8192);
    _Float16* Ws1h = Wo1h + 409600;
    _Float16* Wo2h = Ws1h + 422400;
    _Float16* Wo3h = Wo2h + 16384;
    _Float16* Ws3h = Wo3h + 16384;

    hipLaunchKernelGGL(pack_kernel, dim3(3858), dim3(256), 0, stream,
                       Whh, Wih, Ws2, Wo1, Ws1, Wo2, Wo3, Ws3, d_ws);
    hipLaunchKernelGGL(uvfa_kernel, dim3(B_), dim3(NT), 0, stream,
                       state, obj, text, bs1, bs2, bs3, bo1, bo2, bo3,
                       emb, b_lstm, WhhT, WihT, W2P,
                       Wo1h, Ws1h, Wo2h, Wo3h, Ws3h, out);
}

// Round 14
// 46.516 us; speedup vs baseline: 1.2058x; 1.2058x over previous
//
#include <hip/hip_runtime.h>

// UVFA_text r14: two ANTI-PHASED 512-thread blocks per CU (grid 512), each
// computing the full pre-P8 state for its b with swapped phase order, then
// half of P8 each. Fast __expf transcendentals. f32 gathers (r13 f16 reverted).

#define B_   256
#define M2_  100
#define R_   128
#define L_   12
#define E_   64
#define NT   512

typedef _Float16 half2v __attribute__((ext_vector_type(2)));
typedef _Float16 f16x8  __attribute__((ext_vector_type(8)));
typedef float    f32x4  __attribute__((ext_vector_type(4)));

__device__ __forceinline__ float sigf(float x)   { return 1.f / (1.f + __expf(-x)); }
__device__ __forceinline__ float tanhff(float x) { float e = __expf(-2.f * x); return (1.f - e) / (1.f + e); }

__device__ __forceinline__ uint pk16(float a, float b) {
    half2v h; h.x = (_Float16)a; h.y = (_Float16)b;
    return __builtin_bit_cast(uint, h);
}

#define PINU4(v) asm volatile("" : "+v"(v.x), "+v"(v.y), "+v"(v.z), "+v"(v.w));

// ---- pack: WhhT16[c][r] (512x128 f16), WihT16[c][e] (512x64 f16), Ws2 u32 pairs ----
__global__ __launch_bounds__(256) void pack_kernel(
    const float* __restrict__ Whh, const float* __restrict__ Wih,
    const float* __restrict__ Ws2, void* __restrict__ wsv)
{
    _Float16* WhhT = (_Float16*)wsv;
    _Float16* WihT = WhhT + 65536;
    uint*     W2P  = (uint*)(WihT + 32768);
    int g = blockIdx.x * 256 + threadIdx.x;
    if (g < 65536) {
        int r = g >> 9, c = g & 511;
        WhhT[c * 128 + r] = (_Float16)Whh[g];
    } else if (g < 98304) {
        int g2 = g - 65536; int e = g2 >> 9, c = g2 & 511;
        WihT[c * 64 + e] = (_Float16)Wih[g2];
    } else if (g < 106496) {
        int g3 = g - 98304; int jp = g3 >> 7, kk = g3 & 127;
        W2P[g3] = pk16(Ws2[(2 * jp) * R_ + kk], Ws2[(2 * jp + 1) * R_ + kk]);
    }
}

__global__ __launch_bounds__(NT) __attribute__((amdgpu_waves_per_eu(4, 4)))
void uvfa_kernel(
    const int* __restrict__ state, const int* __restrict__ obj, const int* __restrict__ text,
    const float* __restrict__ Ws1, const float* __restrict__ bs1,
    const float* __restrict__ bs2, const float* __restrict__ Ws3, const float* __restrict__ bs3,
    const float* __restrict__ Wo1, const float* __restrict__ bo1,
    const float* __restrict__ Wo2, const float* __restrict__ bo2,
    const float* __restrict__ Wo3, const float* __restrict__ bo3,
    const float* __restrict__ emb, const float* __restrict__ b_lstm,
    const _Float16* __restrict__ WhhT, const _Float16* __restrict__ WihT,
    const uint* __restrict__ W2P,
    float* __restrict__ out)
{
    const int b      = blockIdx.x & 255;
    const int parity = blockIdx.x >> 8;
    const int tid    = threadIdx.x;

    // U: phase A = xw f32 [12][512] (0..6143) + xemb f32 [16][66] (8192..9247)
    //    phase B = Ws2P u32 [64][132] (0..8447) + h1P u32 [112][68] (8448..16063)
    __shared__ __align__(16) uint  U[16064];
    __shared__ __align__(16) float part[NT];
    __shared__ __align__(16) float hbuf[R_];
    __shared__ __align__(16) uint  hpair[R_ / 2];
    __shared__ __align__(16) float tmp[R_], tmp2[R_], o3buf[R_], wbuf[R_], ubuf[R_], bsbuf[R_];
    __shared__ float redw2[2][112];
    __shared__ int   idx_o[M2_], idx_s[M2_], tids[L_];
    __shared__ float c0s;

    float* xw   = (float*)U;            // [12][512]
    float* xemb = (float*)(U + 8192);   // [16][66]

    const int lane = tid & 63;
    const int wv   = tid >> 6;          // 0..7
    const int m16  = lane & 15;
    const int kgrp = lane >> 4;         // 0..3
    const int k = tid & 127, qq = tid >> 7;   // qq 0..3

    // ---------------- P1: ids + init (common) ----------------
    if (tid < M2_) idx_o[tid] = obj[b * M2_ + tid];
    else if (tid >= 128 && tid < 128 + M2_) idx_s[tid - 128] = state[b * M2_ + tid - 128];
    else if (tid >= 256 && tid < 256 + L_) tids[tid - 256] = text[b * L_ + tid - 256];
    else if (tid >= 384 && tid < 448) hpair[tid - 384] = 0u;
    __syncthreads();

    // ================= track lambdas =================
    auto do_lstm = [&]() {
        // xemb staging
        for (int i = tid; i < L_ * E_; i += NT)
            xemb[(i >> 6) * 66 + (i & 63)] = emb[tids[i >> 6] * E_ + (i & 63)];
        if (tid < 264) ((float*)(U + 8192 + 792))[tid] = 0.f;   // rows 12..15
        __syncthreads();
        // P2: xw = b_lstm + x @ Wih via MFMA (8 waves x 4 col-tiles)
        {
            f16x8 ax[2];
            #pragma unroll
            for (int s = 0; s < 2; ++s)
                #pragma unroll
                for (int e = 0; e < 8; ++e)
                    ax[s][e] = (_Float16)xemb[m16 * 66 + s * 32 + kgrp * 8 + e];
            #pragma unroll
            for (int h = 0; h < 4; ++h) {
                int col = (wv * 4 + h) * 16 + m16;
                float bl = b_lstm[col];
                f32x4 acc = { bl, bl, bl, bl };
                #pragma unroll
                for (int s = 0; s < 2; ++s) {
                    f16x8 bx = *(const f16x8*)&WihT[col * 64 + s * 32 + kgrp * 8];
                    acc = __builtin_amdgcn_mfma_f32_16x16x32_f16(ax[s], bx, acc, 0, 0, 0);
                }
                if (kgrp < 3) {
                    #pragma unroll
                    for (int r = 0; r < 4; ++r)
                        xw[(kgrp * 4 + r) * 512 + col] = acc[r];
                }
            }
        }
        // A-fragments (8 waves x 4 gate-tiles), pinned
        uint4 afu[4][4];
        #pragma unroll
        for (int g = 0; g < 4; ++g) {
            int col = (wv + 8 * g) * 16 + m16;
            #pragma unroll
            for (int s = 0; s < 4; ++s) {
                afu[g][s] = *(const uint4*)&WhhT[col * 128 + s * 32 + kgrp * 8];
                PINU4(afu[g][s])
            }
        }
        __syncthreads();
        // 12 steps
        float cst = 0.f;
        for (int t = 0; t < L_; ++t) {
            f16x8 bf[4];
            #pragma unroll
            for (int s = 0; s < 4; ++s)
                bf[s] = __builtin_bit_cast(f16x8, *(const uint4*)&hpair[s * 16 + kgrp * 4]);
            #pragma unroll
            for (int g = 0; g < 4; ++g) {
                int colb = (wv + 8 * g) * 16 + kgrp * 4;
                f32x4 acc = *(const f32x4*)&xw[t * 512 + colb];
                #pragma unroll
                for (int s = 0; s < 4; ++s)
                    acc = __builtin_amdgcn_mfma_f32_16x16x32_f16(
                        __builtin_bit_cast(f16x8, afu[g][s]), bf[s], acc, 0, 0, 0);
                if (m16 == 0) {
                    part[colb + 0] = acc[0];
                    part[colb + 1] = acc[1];
                    part[colb + 2] = acc[2];
                    part[colb + 3] = acc[3];
                }
            }
            __syncthreads();
            if (tid < R_) {
                float gi = part[tid], gf = part[R_ + tid], gg = part[2 * R_ + tid], go = part[3 * R_ + tid];
                cst = sigf(gf) * cst + sigf(gi) * tanhff(gg);
                float hn = sigf(go) * tanhff(cst);
                hbuf[tid] = hn;
                float hs = __shfl_down(hn, 1, 64);
                if (!(tid & 1)) hpair[tid >> 1] = pk16(hn, hs);
            }
            __syncthreads();
        }
        // stage Ws2P [64][132] (xw dead)
        {
            const uint4* src = (const uint4*)W2P;
            #pragma unroll
            for (int idx = tid; idx < 2048; idx += NT) {
                uint4 v = src[idx];
                int jp = idx >> 5, kq = idx & 31;
                *(uint4*)&U[jp * 132 + kq * 4] = v;
            }
        }
    };

    auto do_objmlp = [&]() {
        {
            float acc = 0.f;
            #pragma unroll 5
            for (int c = qq * 25; c < qq * 25 + 25; ++c)
                acc += Wo1[(c * 32 + idx_o[c]) * R_ + k];
            part[qq * R_ + k] = acc;
        }
        __syncthreads();
        if (tid < R_)
            tmp[tid] = fmaxf(bo1[tid] + part[tid] + part[R_ + tid] + part[2 * R_ + tid] + part[3 * R_ + tid], 0.f);
        __syncthreads();
        {
            float s0 = 0.f, s1 = 0.f, s2 = 0.f, s3 = 0.f;
            int j0 = qq * 32;
            #pragma unroll
            for (int j = 0; j < 32; j += 4) {
                s0 = fmaf(tmp[j0 + j + 0], Wo2[(j0 + j + 0) * R_ + k], s0);
                s1 = fmaf(tmp[j0 + j + 1], Wo2[(j0 + j + 1) * R_ + k], s1);
                s2 = fmaf(tmp[j0 + j + 2], Wo2[(j0 + j + 2) * R_ + k], s2);
                s3 = fmaf(tmp[j0 + j + 3], Wo2[(j0 + j + 3) * R_ + k], s3);
            }
            part[qq * R_ + k] = (s0 + s1) + (s2 + s3);
        }
        __syncthreads();
        if (tid < R_)
            tmp2[tid] = fmaxf(bo2[tid] + part[tid] + part[R_ + tid] + part[2 * R_ + tid] + part[3 * R_ + tid], 0.f);
        __syncthreads();
        {
            float s0 = 0.f, s1 = 0.f, s2 = 0.f, s3 = 0.f;
            int j0 = qq * 32;
            #pragma unroll
            for (int j = 0; j < 32; j += 4) {
                s0 = fmaf(tmp2[j0 + j + 0], Wo3[(j0 + j + 0) * R_ + k], s0);
                s1 = fmaf(tmp2[j0 + j + 1], Wo3[(j0 + j + 1) * R_ + k], s1);
                s2 = fmaf(tmp2[j0 + j + 2], Wo3[(j0 + j + 2) * R_ + k], s2);
                s3 = fmaf(tmp2[j0 + j + 3], Wo3[(j0 + j + 3) * R_ + k], s3);
            }
            part[qq * R_ + k] = (s0 + s1) + (s2 + s3);
        }
        __syncthreads();
        if (tid < R_)
            o3buf[tid] = bo3[tid] + part[tid] + part[R_ + tid] + part[2 * R_ + tid] + part[3 * R_ + tid];
        __syncthreads();
    };

    auto do_bases = [&]() {
        {
            float acc = 0.f;
            #pragma unroll 5
            for (int c = qq * 25; c < qq * 25 + 25; ++c)
                acc += Ws1[(c * 33 + idx_s[c]) * R_ + k];
            part[qq * R_ + k] = acc;
        }
        __syncthreads();
        if (tid < R_)
            bsbuf[tid] = bs1[tid] + part[tid] + part[R_ + tid] + part[2 * R_ + tid] + part[3 * R_ + tid];
        __syncthreads();
    };

    auto do_h1p = [&]() {
        #pragma unroll 5
        for (int pass = 0; pass < 25; ++pass) {
            int idx = pass * NT + tid;
            int j = idx & 127, p = idx >> 7;
            float v = fmaxf(bsbuf[j] + Ws1[(p * 33 + 32) * R_ + j], 0.f);
            float v2 = __shfl_down(v, 1, 64);
            if (!(j & 1)) U[8448 + p * 68 + (j >> 1)] = pk16(v, v2);
        }
        for (int i = tid; i < 816; i += NT) U[8448 + 6800 + i] = 0u;
    };

    // ================= anti-phased tracks =================
    if (!parity) {
        do_lstm();
        do_objmlp();
        do_bases();
        do_h1p();
    } else {
        do_objmlp();
        do_bases();
        do_lstm();
        do_h1p();
    }
    __syncthreads();

    // ================= join: w = o3*h ; u ; c0 =================
    if (tid < R_) wbuf[tid] = o3buf[tid] * hbuf[tid];
    __syncthreads();
    {
        float s0 = 0.f, s1 = 0.f, s2 = 0.f, s3 = 0.f;
        const float4* w4 = reinterpret_cast<const float4*>(&Ws3[k * R_ + qq * 32]);
        #pragma unroll
        for (int jj = 0; jj < 8; ++jj) {
            float4 v = w4[jj];
            int j0 = qq * 32 + jj * 4;
            s0 = fmaf(v.x, wbuf[j0 + 0], s0);
            s1 = fmaf(v.y, wbuf[j0 + 1], s1);
            s2 = fmaf(v.z, wbuf[j0 + 2], s2);
            s3 = fmaf(v.w, wbuf[j0 + 3], s3);
        }
        part[qq * R_ + k] = (s0 + s1) + (s2 + s3);
    }
    if (tid >= 448) {
        int j = tid - 448;
        float s = bs3[j] * wbuf[j] + bs3[j + 64] * wbuf[j + 64];
        s += __shfl_down(s, 32, 64);
        s += __shfl_down(s, 16, 64);
        s += __shfl_down(s, 8, 64);
        s += __shfl_down(s, 4, 64);
        s += __shfl_down(s, 2, 64);
        s += __shfl_down(s, 1, 64);
        if (j == 0) c0s = s;
    }
    __syncthreads();
    if (tid < R_)
        ubuf[tid] = part[tid] + part[R_ + tid] + part[2 * R_ + tid] + part[3 * R_ + tid];
    __syncthreads();

    // ================= P8 (half per parity) =================
    {
        const int nmt = parity ? 3 : 4;          // mtiles this block owns
        const int mt0 = parity ? 4 : 0;
        if (wv < 2 * nmt) {
            const int mtile = mt0 + (wv >> 1), nhalf = wv & 1;
            const uint* Ap = U + 8448 + (mtile * 16 + m16) * 68;
            f16x8 A[4];
            #pragma unroll
            for (int s = 0; s < 4; ++s)
                A[s] = __builtin_bit_cast(f16x8, *(const uint4*)&Ap[s * 16 + kgrp * 4]);
            f32x4 acc[4] = { {0,0,0,0}, {0,0,0,0}, {0,0,0,0}, {0,0,0,0} };
            #pragma unroll
            for (int nt = 0; nt < 4; ++nt) {
                int ko = (nhalf * 4 + nt) * 16 + m16;
                #pragma unroll
                for (int s = 0; s < 4; ++s) {
                    const uint* Bp = U + (s * 16 + kgrp * 4) * 132 + ko;
                    uint4 bv = { Bp[0], Bp[132], Bp[264], Bp[396] };
                    acc[nt] = __builtin_amdgcn_mfma_f32_16x16x32_f16(
                        A[s], __builtin_bit_cast(f16x8, bv), acc[nt], 0, 0, 0);
                }
            }
            float vs0 = 0.f, vs1 = 0.f, vs2 = 0.f, vs3 = 0.f;
            #pragma unroll
            for (int nt = 0; nt < 4; ++nt) {
                int ko = (nhalf * 4 + nt) * 16 + m16;
                float bb = bs2[ko], uu = ubuf[ko];
                vs0 = fmaf(fmaxf(acc[nt][0] + bb, 0.f), uu, vs0);
                vs1 = fmaf(fmaxf(acc[nt][1] + bb, 0.f), uu, vs1);
                vs2 = fmaf(fmaxf(acc[nt][2] + bb, 0.f), uu, vs2);
                vs3 = fmaf(fmaxf(acc[nt][3] + bb, 0.f), uu, vs3);
            }
            vs0 += __shfl_xor(vs0, 1, 64); vs0 += __shfl_xor(vs0, 2, 64);
            vs0 += __shfl_xor(vs0, 4, 64); vs0 += __shfl_xor(vs0, 8, 64);
            vs1 += __shfl_xor(vs1, 1, 64); vs1 += __shfl_xor(vs1, 2, 64);
            vs1 += __shfl_xor(vs1, 4, 64); vs1 += __shfl_xor(vs1, 8, 64);
            vs2 += __shfl_xor(vs2, 1, 64); vs2 += __shfl_xor(vs2, 2, 64);
            vs2 += __shfl_xor(vs2, 4, 64); vs2 += __shfl_xor(vs2, 8, 64);
            vs3 += __shfl_xor(vs3, 1, 64); vs3 += __shfl_xor(vs3, 2, 64);
            vs3 += __shfl_xor(vs3, 4, 64); vs3 += __shfl_xor(vs3, 8, 64);
            if (m16 == 0) {
                int pr = mtile * 16 + kgrp * 4;
                redw2[nhalf][pr + 0] = vs0;
                redw2[nhalf][pr + 1] = vs1;
                redw2[nhalf][pr + 2] = vs2;
                redw2[nhalf][pr + 3] = vs3;
            }
        }
    }
    __syncthreads();

    {
        const int p0 = parity ? 64 : 0;
        const int p1 = parity ? M2_ : 64;
        if (tid >= p0 && tid < p1)
            out[b * M2_ + tid] = c0s + redw2[0][tid] + redw2[1][tid];
    }
}

extern "C" void kernel_launch(void* const* d_in, const int* in_sizes, int n_in,
                              void* d_out, int out_size, void* d_ws, size_t ws_size,
                              hipStream_t stream) {
    const int*   state  = (const int*)d_in[0];
    const int*   obj    = (const int*)d_in[1];
    const int*   text   = (const int*)d_in[2];
    const float* Ws1    = (const float*)d_in[3];
    const float* bs1    = (const float*)d_in[4];
    const float* Ws2    = (const float*)d_in[5];
    const float* bs2    = (const float*)d_in[6];
    const float* Ws3    = (const float*)d_in[7];
    const float* bs3    = (const float*)d_in[8];
    const float* Wo1    = (const float*)d_in[9];
    const float* bo1    = (const float*)d_in[10];
    const float* Wo2    = (const float*)d_in[11];
    const float* bo2    = (const float*)d_in[12];
    const float* Wo3    = (const float*)d_in[13];
    const float* bo3    = (const float*)d_in[14];
    const float* emb    = (const float*)d_in[15];
    const float* Wih    = (const float*)d_in[16];
    const float* Whh    = (const float*)d_in[17];
    const float* b_lstm = (const float*)d_in[18];
    float* out = (float*)d_out;

    _Float16* WhhT = (_Float16*)d_ws;
    _Float16* WihT = WhhT + 65536;
    uint*     W2P  = (uint*)(WihT + 32768);

    hipLaunchKernelGGL(pack_kernel, dim3(416), dim3(256), 0, stream, Whh, Wih, Ws2, d_ws);
    hipLaunchKernelGGL(uvfa_kernel, dim3(512), dim3(NT), 0, stream,
                       state, obj, text, Ws1, bs1, bs2, Ws3, bs3,
                       Wo1, bo1, Wo2, bo2, Wo3, bo3, emb, b_lstm,
                       WhhT, WihT, W2P, out);
}

// Round 15
// 44.855 us; speedup vs baseline: 1.2504x; 1.0370x over previous
//
#include <hip/hip_runtime.h>

// UVFA_text r15: single 1024-thread block per b (grid 256). Wave specialization:
// waves 0-7 run the in-lane MFMA LSTM (12 steps, 1 barrier/step) while waves
// 8-15 execute a 12-slot prep schedule (Ws2P staging, Wo1 gather+reduce,
// Ws1 base_s gather+reduce) in the same barrier domain. xw/Ws2P/h1P coexist
// in a 89KB LDS union. Post-LSTM: objL2/L3 -> w -> {u || h1P} -> P8 MFMA.

#define B_   256
#define M2_  100
#define R_   128
#define L_   12
#define E_   64
#define NT   1024

typedef _Float16 half2v __attribute__((ext_vector_type(2)));
typedef _Float16 f16x8  __attribute__((ext_vector_type(8)));
typedef float    f32x4  __attribute__((ext_vector_type(4)));

__device__ __forceinline__ float sigf(float x)   { return 1.f / (1.f + __expf(-x)); }
__device__ __forceinline__ float tanhff(float x) { float e = __expf(-2.f * x); return (1.f - e) / (1.f + e); }

__device__ __forceinline__ uint pk16(float a, float b) {
    half2v h; h.x = (_Float16)a; h.y = (_Float16)b;
    return __builtin_bit_cast(uint, h);
}

#define PINU4(v) asm volatile("" : "+v"(v.x), "+v"(v.y), "+v"(v.z), "+v"(v.w));

// ---- pack: WhhT16[c][r] (512x128 f16), WihT16[c][e] (512x64 f16), Ws2 u32 pairs ----
__global__ __launch_bounds__(256) void pack_kernel(
    const float* __restrict__ Whh, const float* __restrict__ Wih,
    const float* __restrict__ Ws2, void* __restrict__ wsv)
{
    _Float16* WhhT = (_Float16*)wsv;
    _Float16* WihT = WhhT + 65536;
    uint*     W2P  = (uint*)(WihT + 32768);
    int g = blockIdx.x * 256 + threadIdx.x;
    if (g < 65536) {
        int r = g >> 9, c = g & 511;
        WhhT[c * 128 + r] = (_Float16)Whh[g];
    } else if (g < 98304) {
        int g2 = g - 65536; int e = g2 >> 9, c = g2 & 511;
        WihT[c * 64 + e] = (_Float16)Wih[g2];
    } else if (g < 106496) {
        int g3 = g - 98304; int jp = g3 >> 7, kk = g3 & 127;
        W2P[g3] = pk16(Ws2[(2 * jp) * R_ + kk], Ws2[(2 * jp + 1) * R_ + kk]);
    }
}

__global__ __launch_bounds__(NT) __attribute__((amdgpu_waves_per_eu(4, 4)))
void uvfa_kernel(
    const int* __restrict__ state, const int* __restrict__ obj, const int* __restrict__ text,
    const float* __restrict__ Ws1, const float* __restrict__ bs1,
    const float* __restrict__ bs2, const float* __restrict__ Ws3, const float* __restrict__ bs3,
    const float* __restrict__ Wo1, const float* __restrict__ bo1,
    const float* __restrict__ Wo2, const float* __restrict__ bo2,
    const float* __restrict__ Wo3, const float* __restrict__ bo3,
    const float* __restrict__ emb, const float* __restrict__ b_lstm,
    const _Float16* __restrict__ WhhT, const _Float16* __restrict__ WihT,
    const uint* __restrict__ W2P,
    float* __restrict__ out)
{
    const int b   = blockIdx.x;
    const int tid = threadIdx.x;

    // U (88.8 KiB union):
    //   xw   f32 [12][512]          = U[0..6143]        (dead after LSTM)
    //   Ws2P u32 [64][132]          = U[6144..14591]
    //   h1P  u32 [112][68]          = U[14592..22207]
    //   xemb f32 [16][66] overlay   = U[14592..15647]   (dead before h1P)
    __shared__ __align__(16) uint  U[22208];
    __shared__ __align__(16) float part[NT];
    __shared__ __align__(16) float hbuf[R_];
    __shared__ __align__(16) uint  hpair[2][64];
    __shared__ __align__(16) float tmp[R_], tmp2[R_], wbuf[R_], ubuf[R_], bsbuf[R_];
    __shared__ float redw2[2][112];
    __shared__ int   idx_o[M2_], idx_s[M2_], tids[L_];
    __shared__ float c0s;

    float* xw   = (float*)U;
    float* xemb = (float*)(U + 14592);

    const int lane = tid & 63;
    const int wv   = tid >> 6;          // 0..15
    const int m16  = lane & 15;
    const int kgrp = lane >> 4;         // 0..3
    const int k    = tid & 127;
    const int qq   = tid >> 7;          // 0..7
    const int tid2 = tid - 512;         // valid for wv>=8
    const int q2u  = (tid >> 7) & 3;    // upper q-group 0..3

    // ---------------- P1: ids + init ----------------
    if (tid < M2_) idx_o[tid] = obj[b * M2_ + tid];
    else if (tid >= 128 && tid < 128 + M2_) idx_s[tid - 128] = state[b * M2_ + tid - 128];
    else if (tid >= 256 && tid < 256 + L_) tids[tid - 256] = text[b * L_ + tid - 256];
    else if (tid >= 384 && tid < 448) hpair[0][tid - 384] = 0u;
    __syncthreads();

    // ---------------- slot A: xemb (lower) || Ws2P staging (upper) ----------------
    if (wv < 8) {
        for (int i = tid; i < 16 * 66; i += 512) {
            int t = i / 66, c = i - t * 66;
            xemb[i] = (c < 64 && t < L_) ? emb[tids[t] * E_ + c] : 0.f;
        }
    } else {
        const uint4* src = (const uint4*)W2P;
        #pragma unroll
        for (int idx = tid2; idx < 2048; idx += 512) {
            uint4 v = src[idx];
            int jp = idx >> 5, kq = idx & 31;
            *(uint4*)&U[6144 + jp * 132 + kq * 4] = v;
        }
    }
    __syncthreads();

    // ---------------- slot B: P2 xw (lower) || obj rows 0..4 (upper) ----------------
    float accO = 0.f, accS = 0.f;
    if (wv < 8) {
        f16x8 ax[2];
        #pragma unroll
        for (int s = 0; s < 2; ++s)
            #pragma unroll
            for (int e = 0; e < 8; ++e)
                ax[s][e] = (_Float16)xemb[m16 * 66 + s * 32 + kgrp * 8 + e];
        #pragma unroll
        for (int h = 0; h < 4; ++h) {
            int col = (wv * 4 + h) * 16 + m16;
            float bl = b_lstm[col];
            f32x4 acc = { bl, bl, bl, bl };
            #pragma unroll
            for (int s = 0; s < 2; ++s) {
                f16x8 bx = *(const f16x8*)&WihT[col * 64 + s * 32 + kgrp * 8];
                acc = __builtin_amdgcn_mfma_f32_16x16x32_f16(ax[s], bx, acc, 0, 0, 0);
            }
            if (kgrp < 3) {
                #pragma unroll
                for (int r = 0; r < 4; ++r)
                    xw[(kgrp * 4 + r) * 512 + col] = acc[r];
            }
        }
    } else {
        int c0r = q2u * 25;
        #pragma unroll
        for (int c = 0; c < 5; ++c)
            accO += Wo1[((c0r + c) * 32 + idx_o[c0r + c]) * R_ + k];
    }

    // ---------------- LSTM A-fragments (lower waves), pinned ----------------
    uint4 afu[4][4];
    if (wv < 8) {
        #pragma unroll
        for (int g = 0; g < 4; ++g) {
            int col = (wv + 8 * g) * 16 + m16;
            #pragma unroll
            for (int s = 0; s < 4; ++s) {
                afu[g][s] = *(const uint4*)&WhhT[col * 128 + s * 32 + kgrp * 8];
                PINU4(afu[g][s])
            }
        }
    }
    __syncthreads();   // xw ready, slot-B prep done

    // ---------------- LSTM loop: lower computes, upper preps ----------------
    float cst0 = 0.f, cst1 = 0.f, cst2 = 0.f, cst3 = 0.f;
    float h0 = 0.f, h1v = 0.f, h2v = 0.f, h3v = 0.f;
    for (int t = 0; t < L_; ++t) {
        if (wv < 8) {
            const uint* hp = hpair[t & 1];
            f16x8 bf[4];
            #pragma unroll
            for (int s = 0; s < 4; ++s)
                bf[s] = __builtin_bit_cast(f16x8, *(const uint4*)&hp[s * 16 + kgrp * 4]);
            f32x4 acc[4];
            #pragma unroll
            for (int g = 0; g < 4; ++g) {
                acc[g] = *(const f32x4*)&xw[t * 512 + (wv + 8 * g) * 16 + kgrp * 4];
                #pragma unroll
                for (int s = 0; s < 4; ++s)
                    acc[g] = __builtin_amdgcn_mfma_f32_16x16x32_f16(
                        __builtin_bit_cast(f16x8, afu[g][s]), bf[s], acc[g], 0, 0, 0);
            }
            cst0 = sigf(acc[1][0]) * cst0 + sigf(acc[0][0]) * tanhff(acc[2][0]);
            h0   = sigf(acc[3][0]) * tanhff(cst0);
            cst1 = sigf(acc[1][1]) * cst1 + sigf(acc[0][1]) * tanhff(acc[2][1]);
            h1v  = sigf(acc[3][1]) * tanhff(cst1);
            cst2 = sigf(acc[1][2]) * cst2 + sigf(acc[0][2]) * tanhff(acc[2][2]);
            h2v  = sigf(acc[3][2]) * tanhff(cst2);
            cst3 = sigf(acc[1][3]) * cst3 + sigf(acc[0][3]) * tanhff(acc[2][3]);
            h3v  = sigf(acc[3][3]) * tanhff(cst3);
            if (m16 == 0) {
                uint* hw = hpair[(t + 1) & 1];
                hw[8 * wv + kgrp * 2]     = pk16(h0, h1v);
                hw[8 * wv + kgrp * 2 + 1] = pk16(h2v, h3v);
            }
        } else {
            int c0r = q2u * 25;
            if (t < 4) {                     // obj rows 5+5t .. 9+5t
                #pragma unroll
                for (int c = 0; c < 5; ++c) {
                    int cr = c0r + 5 + 5 * t + c;
                    accO += Wo1[(cr * 32 + idx_o[cr]) * R_ + k];
                }
            } else if (t == 4) {
                part[tid2] = accO;
            } else if (t == 5) {
                if (tid2 < R_)
                    tmp[tid2] = fmaxf(bo1[tid2] + part[tid2] + part[128 + tid2] + part[256 + tid2] + part[384 + tid2], 0.f);
                #pragma unroll
                for (int c = 0; c < 5; ++c)
                    accS += Ws1[((c0r + c) * 33 + idx_s[c0r + c]) * R_ + k];
            } else if (t < 10) {             // bs rows 5+5(t-6) .. 9+5(t-6)
                #pragma unroll
                for (int c = 0; c < 5; ++c) {
                    int cr = c0r + 5 + 5 * (t - 6) + c;
                    accS += Ws1[(cr * 33 + idx_s[cr]) * R_ + k];
                }
            } else if (t == 10) {
                part[tid2] = accS;
            } else {                          // t == 11
                if (tid2 < R_)
                    bsbuf[tid2] = bs1[tid2] + part[tid2] + part[128 + tid2] + part[256 + tid2] + part[384 + tid2];
            }
        }
        __syncthreads();
    }

    // ---------------- publish h ----------------
    if (wv < 8 && m16 == 0) {
        int j = wv * 16 + kgrp * 4;
        hbuf[j + 0] = h0;
        hbuf[j + 1] = h1v;
        hbuf[j + 2] = h2v;
        hbuf[j + 3] = h3v;
    }
    __syncthreads();

    // ---------------- obj L2 (8 q-groups x 16 j) ----------------
    {
        float s0 = 0.f, s1 = 0.f, s2 = 0.f, s3 = 0.f;
        int j0 = qq * 16;
        #pragma unroll
        for (int j = 0; j < 16; j += 4) {
            s0 = fmaf(tmp[j0 + j + 0], Wo2[(j0 + j + 0) * R_ + k], s0);
            s1 = fmaf(tmp[j0 + j + 1], Wo2[(j0 + j + 1) * R_ + k], s1);
            s2 = fmaf(tmp[j0 + j + 2], Wo2[(j0 + j + 2) * R_ + k], s2);
            s3 = fmaf(tmp[j0 + j + 3], Wo2[(j0 + j + 3) * R_ + k], s3);
        }
        part[qq * R_ + k] = (s0 + s1) + (s2 + s3);
    }
    __syncthreads();
    if (tid < R_) {
        float a = bo2[tid];
        #pragma unroll
        for (int q8 = 0; q8 < 8; ++q8) a += part[q8 * R_ + tid];
        tmp2[tid] = fmaxf(a, 0.f);
    }
    __syncthreads();
    // ---------------- obj L3 ----------------
    {
        float s0 = 0.f, s1 = 0.f, s2 = 0.f, s3 = 0.f;
        int j0 = qq * 16;
        #pragma unroll
        for (int j = 0; j < 16; j += 4) {
            s0 = fmaf(tmp2[j0 + j + 0], Wo3[(j0 + j + 0) * R_ + k], s0);
            s1 = fmaf(tmp2[j0 + j + 1], Wo3[(j0 + j + 1) * R_ + k], s1);
            s2 = fmaf(tmp2[j0 + j + 2], Wo3[(j0 + j + 2) * R_ + k], s2);
            s3 = fmaf(tmp2[j0 + j + 3], Wo3[(j0 + j + 3) * R_ + k], s3);
        }
        part[qq * R_ + k] = (s0 + s1) + (s2 + s3);
    }
    __syncthreads();
    if (tid < R_) {
        float a = bo3[tid];
        #pragma unroll
        for (int q8 = 0; q8 < 8; ++q8) a += part[q8 * R_ + tid];
        wbuf[tid] = a * hbuf[tid];
    }
    __syncthreads();

    // ---------------- u partials + c0  ||  h1P staging ----------------
    {
        float s0 = 0.f, s1 = 0.f, s2 = 0.f, s3 = 0.f;
        int j0 = qq * 16;
        const float4* w3 = reinterpret_cast<const float4*>(&Ws3[k * R_ + j0]);
        #pragma unroll
        for (int jj = 0; jj < 4; ++jj) {
            float4 v = w3[jj];
            s0 = fmaf(v.x, wbuf[j0 + jj * 4 + 0], s0);
            s1 = fmaf(v.y, wbuf[j0 + jj * 4 + 1], s1);
            s2 = fmaf(v.z, wbuf[j0 + jj * 4 + 2], s2);
            s3 = fmaf(v.w, wbuf[j0 + jj * 4 + 3], s3);
        }
        part[qq * R_ + k] = (s0 + s1) + (s2 + s3);
    }
    if (tid >= 960) {
        int j = tid - 960;
        float s = bs3[j] * wbuf[j] + bs3[j + 64] * wbuf[j + 64];
        s += __shfl_down(s, 32, 64);
        s += __shfl_down(s, 16, 64);
        s += __shfl_down(s, 8, 64);
        s += __shfl_down(s, 4, 64);
        s += __shfl_down(s, 2, 64);
        s += __shfl_down(s, 1, 64);
        if (j == 0) c0s = s;
    }
    #pragma unroll 4
    for (int pass = 0; pass < 13; ++pass) {
        int idx = pass * NT + tid;
        if (idx < M2_ * R_) {
            int j = idx & 127, p = idx >> 7;
            float v = fmaxf(bsbuf[j] + Ws1[(p * 33 + 32) * R_ + j], 0.f);
            float v2 = __shfl_down(v, 1, 64);
            if (!(j & 1)) U[14592 + p * 68 + (j >> 1)] = pk16(v, v2);
        }
    }
    if (tid < 816) U[14592 + 6800 + tid] = 0u;   // zero h1P rows 100..111
    __syncthreads();
    if (tid < R_) {
        float a = 0.f;
        #pragma unroll
        for (int q8 = 0; q8 < 8; ++q8) a += part[q8 * R_ + tid];
        ubuf[tid] = a;
    }
    __syncthreads();

    // ---------------- P8: h2 = h1 @ Ws2 via MFMA; wave = (mtile, nhalf) ----------------
    if (wv < 14) {
        const int mtile = wv >> 1, nhalf = wv & 1;
        const uint* Ap = U + 14592 + (mtile * 16 + m16) * 68;
        f16x8 A[4];
        #pragma unroll
        for (int s = 0; s < 4; ++s)
            A[s] = __builtin_bit_cast(f16x8, *(const uint4*)&Ap[s * 16 + kgrp * 4]);
        f32x4 acc[4] = { {0,0,0,0}, {0,0,0,0}, {0,0,0,0}, {0,0,0,0} };
        #pragma unroll
        for (int nt = 0; nt < 4; ++nt) {
            int ko = (nhalf * 4 + nt) * 16 + m16;
            #pragma unroll
            for (int s = 0; s < 4; ++s) {
                const uint* Bp = U + 6144 + (s * 16 + kgrp * 4) * 132 + ko;
                uint4 bv = { Bp[0], Bp[132], Bp[264], Bp[396] };
                acc[nt] = __builtin_amdgcn_mfma_f32_16x16x32_f16(
                    A[s], __builtin_bit_cast(f16x8, bv), acc[nt], 0, 0, 0);
            }
        }
        float vs0 = 0.f, vs1 = 0.f, vs2 = 0.f, vs3 = 0.f;
        #pragma unroll
        for (int nt = 0; nt < 4; ++nt) {
            int ko = (nhalf * 4 + nt) * 16 + m16;
            float bb = bs2[ko], uu = ubuf[ko];
            vs0 = fmaf(fmaxf(acc[nt][0] + bb, 0.f), uu, vs0);
            vs1 = fmaf(fmaxf(acc[nt][1] + bb, 0.f), uu, vs1);
            vs2 = fmaf(fmaxf(acc[nt][2] + bb, 0.f), uu, vs2);
            vs3 = fmaf(fmaxf(acc[nt][3] + bb, 0.f), uu, vs3);
        }
        vs0 += __shfl_xor(vs0, 1, 64); vs0 += __shfl_xor(vs0, 2, 64);
        vs0 += __shfl_xor(vs0, 4, 64); vs0 += __shfl_xor(vs0, 8, 64);
        vs1 += __shfl_xor(vs1, 1, 64); vs1 += __shfl_xor(vs1, 2, 64);
        vs1 += __shfl_xor(vs1, 4, 64); vs1 += __shfl_xor(vs1, 8, 64);
        vs2 += __shfl_xor(vs2, 1, 64); vs2 += __shfl_xor(vs2, 2, 64);
        vs2 += __shfl_xor(vs2, 4, 64); vs2 += __shfl_xor(vs2, 8, 64);
        vs3 += __shfl_xor(vs3, 1, 64); vs3 += __shfl_xor(vs3, 2, 64);
        vs3 += __shfl_xor(vs3, 4, 64); vs3 += __shfl_xor(vs3, 8, 64);
        if (m16 == 0) {
            int pr = mtile * 16 + kgrp * 4;
            redw2[nhalf][pr + 0] = vs0;
            redw2[nhalf][pr + 1] = vs1;
            redw2[nhalf][pr + 2] = vs2;
            redw2[nhalf][pr + 3] = vs3;
        }
    }
    __syncthreads();

    if (tid < M2_)
        out[b * M2_ + tid] = c0s + redw2[0][tid] + redw2[1][tid];
}

extern "C" void kernel_launch(void* const* d_in, const int* in_sizes, int n_in,
                              void* d_out, int out_size, void* d_ws, size_t ws_size,
                              hipStream_t stream) {
    const int*   state  = (const int*)d_in[0];
    const int*   obj    = (const int*)d_in[1];
    const int*   text   = (const int*)d_in[2];
    const float* Ws1    = (const float*)d_in[3];
    const float* bs1    = (const float*)d_in[4];
    const float* Ws2    = (const float*)d_in[5];
    const float* bs2    = (const float*)d_in[6];
    const float* Ws3    = (const float*)d_in[7];
    const float* bs3    = (const float*)d_in[8];
    const float* Wo1    = (const float*)d_in[9];
    const float* bo1    = (const float*)d_in[10];
    const float* Wo2    = (const float*)d_in[11];
    const float* bo2    = (const float*)d_in[12];
    const float* Wo3    = (const float*)d_in[13];
    const float* bo3    = (const float*)d_in[14];
    const float* emb    = (const float*)d_in[15];
    const float* Wih    = (const float*)d_in[16];
    const float* Whh    = (const float*)d_in[17];
    const float* b_lstm = (const float*)d_in[18];
    float* out = (float*)d_out;

    _Float16* WhhT = (_Float16*)d_ws;
    _Float16* WihT = WhhT + 65536;
    uint*     W2P  = (uint*)(WihT + 32768);

    hipLaunchKernelGGL(pack_kernel, dim3(416), dim3(256), 0, stream, Whh, Wih, Ws2, d_ws);
    hipLaunchKernelGGL(uvfa_kernel, dim3(B_), dim3(NT), 0, stream,
                       state, obj, text, Ws1, bs1, bs2, Ws3, bs3,
                       Wo1, bo1, Wo2, bo2, Wo3, bo3, emb, b_lstm,
                       WhhT, WihT, W2P, out);
}

// Round 16
// 41.351 us; speedup vs baseline: 1.3564x; 1.0847x over previous
//
#include <hip/hip_runtime.h>

// UVFA_text r16: r10 main kernel UNCHANGED (best-known, 39.9us) + a streaming
// "touch" kernel that pre-reads all weight tables coalesced at full HBM BW,
// landing them in L3 so the main kernel's scattered gathers hit L3 not HBM.
// (Harness flushes L2/L3 with a 268MB fill between replays — every replay the
// weights are cache-cold; touch re-warms them in ~2us.)

#define B_   256
#define M2_  100
#define R_   128
#define L_   12
#define E_   64
#define NT   1024

typedef _Float16 half2v __attribute__((ext_vector_type(2)));
typedef _Float16 f16x8  __attribute__((ext_vector_type(8)));
typedef float    f32x4  __attribute__((ext_vector_type(4)));

__device__ __forceinline__ float sigf(float x) { return 1.f / (1.f + expf(-x)); }

__device__ __forceinline__ uint pk16(float a, float b) {
    half2v h; h.x = (_Float16)a; h.y = (_Float16)b;
    return __builtin_bit_cast(uint, h);
}

// ---- touch: coalesced stream-read of all gather/row weight tables -> L3 ----
__global__ __launch_bounds__(256) void touch_kernel(
    const float* __restrict__ Wo1, const float* __restrict__ Ws1,
    const float* __restrict__ Wo2, const float* __restrict__ Wo3,
    const float* __restrict__ Ws3, const float* __restrict__ emb,
    float* __restrict__ sink)
{
    const float4* a0 = (const float4*)Wo1;   // 102400 float4
    const float4* a1 = (const float4*)Ws1;   // 105600
    const float4* a2 = (const float4*)Wo2;   // 4096
    const float4* a3 = (const float4*)Wo3;   // 4096
    const float4* a4 = (const float4*)Ws3;   // 4096
    const float4* a5 = (const float4*)emb;   // 16000
    float s = 0.f;
    int g = blockIdx.x * 256 + threadIdx.x;
    int stride = gridDim.x * 256;
    for (int i = g; i < 102400; i += stride) { float4 v = a0[i]; s += v.x + v.y + v.z + v.w; }
    for (int i = g; i < 105600; i += stride) { float4 v = a1[i]; s += v.x + v.y + v.z + v.w; }
    for (int i = g; i < 16000; i += stride)  { float4 v = a5[i]; s += v.x + v.w; }
    if (g < 4096) { float4 v = a2[g]; s += v.x; }
    if (g < 4096) { float4 v = a3[g]; s += v.y; }
    if (g < 4096) { float4 v = a4[g]; s += v.z; }
    // conditional sink: compiler cannot DCE the loads; write is deterministic
    if (s == 123456789.0f) sink[g & 1023] = s;
}

// ---- pack: WhhT16[c][r] (512x128 f16), WihT16[c][e] (512x64 f16), Ws2P u32 pairs ----
__global__ __launch_bounds__(256) void pack_kernel(
    const float* __restrict__ Whh, const float* __restrict__ Wih,
    const float* __restrict__ Ws2, void* __restrict__ wsv)
{
    _Float16* WhhT = (_Float16*)wsv;            // [512][128]
    _Float16* WihT = WhhT + 65536;              // [512][64]
    uint*     W2P  = (uint*)(WihT + 32768);     // [64][128]
    int g = blockIdx.x * 256 + threadIdx.x;
    if (g < 65536) {
        int r = g >> 9, c = g & 511;            // coalesced read
        WhhT[c * 128 + r] = (_Float16)Whh[r * 512 + c];
    } else if (g < 65536 + 32768) {
        int g2 = g - 65536;
        int e = g2 >> 9, c = g2 & 511;
        WihT[c * 64 + e] = (_Float16)Wih[e * 512 + c];
    } else if (g < 65536 + 32768 + 8192) {
        int g3 = g - 65536 - 32768;
        int jp = g3 >> 7, kk = g3 & 127;
        W2P[g3] = pk16(Ws2[(2 * jp) * R_ + kk], Ws2[(2 * jp + 1) * R_ + kk]);
    }
}

__global__ __launch_bounds__(NT) __attribute__((amdgpu_waves_per_eu(4, 4)))
void uvfa_kernel(
    const int* __restrict__ state, const int* __restrict__ obj, const int* __restrict__ text,
    const float* __restrict__ Ws1, const float* __restrict__ bs1,
    const float* __restrict__ bs2, const float* __restrict__ Ws3, const float* __restrict__ bs3,
    const float* __restrict__ Wo1, const float* __restrict__ bo1,
    const float* __restrict__ Wo2, const float* __restrict__ bo2,
    const float* __restrict__ Wo3, const float* __restrict__ bo3,
    const float* __restrict__ emb, const float* __restrict__ b_lstm,
    const _Float16* __restrict__ WhhT, const _Float16* __restrict__ WihT,
    const uint* __restrict__ W2P,
    float* __restrict__ out)
{
    const int b   = blockIdx.x;
    const int tid = threadIdx.x;

    // U: phase A = xw f32 [16][512] (0..8191); xemb f32 [16][66] (8192..9247)
    //    phase B = Ws2P u32 [64][132] (0..8447) + h1P u32 [112][68] (8448..16063)
    __shared__ __align__(16) uint  U[16064];
    __shared__ __align__(16) float part[NT];
    __shared__ __align__(16) float hbuf[R_];
    __shared__ __align__(16) uint  hpair[R_ / 2];
    __shared__ __align__(16) float tmp[R_], tmp2[R_], wbuf[R_], ubuf[R_], bsbuf[R_];
    __shared__ float redw2[2][112];
    __shared__ int   idx_o[M2_], idx_s[M2_], tids[L_];
    __shared__ float c0s;

    float* xw   = (float*)U;            // [16][512]
    float* xemb = (float*)(U + 8192);   // [16][66], rows 12..15 zero

    const int lane = tid & 63;
    const int wv   = tid >> 6;          // 0..15
    const int m16  = lane & 15;
    const int kgrp = lane >> 4;         // 0..3
    const int k = tid & 127, qq = tid >> 7;   // qq 0..7

    // ---------- LSTM A-fragments: contiguous dwordx4 from WhhT16 ----------
    f16x8 af[2][4];
    #pragma unroll
    for (int tt = 0; tt < 2; ++tt) {
        int col = (2 * wv + tt) * 16 + m16;
        #pragma unroll
        for (int s = 0; s < 4; ++s)
            af[tt][s] = *(const f16x8*)&WhhT[col * 128 + s * 32 + kgrp * 8];
    }

    // ---------- P1: ids + init ----------
    if (tid < M2_) idx_o[tid] = obj[b * M2_ + tid];
    else if (tid >= 128 && tid < 128 + M2_) idx_s[tid - 128] = state[b * M2_ + tid - 128];
    else if (tid >= 256 && tid < 256 + L_) tids[tid - 256] = text[b * L_ + tid - 256];
    else if (tid >= 384 && tid < 448) hpair[tid - 384] = 0u;
    __syncthreads();
    if (tid < L_ * E_) xemb[(tid >> 6) * 66 + (tid & 63)] = emb[tids[tid >> 6] * E_ + (tid & 63)];
    else if (tid < L_ * E_ + 264) ((float*)(U + 8192 + 792))[tid - L_ * E_] = 0.f;  // rows 12..15
    __syncthreads();

    // ---------- P2: xw = b_lstm + x @ Wih via MFMA ----------
    {
        f16x8 ax[2];
        #pragma unroll
        for (int s = 0; s < 2; ++s) {
            #pragma unroll
            for (int e = 0; e < 8; ++e)
                ax[s][e] = (_Float16)xemb[m16 * 66 + s * 32 + kgrp * 8 + e];
        }
        #pragma unroll
        for (int h = 0; h < 2; ++h) {
            int col = (wv * 2 + h) * 16 + m16;
            float bl = b_lstm[col];
            f32x4 acc = { bl, bl, bl, bl };
            #pragma unroll
            for (int s = 0; s < 2; ++s) {
                f16x8 bx = *(const f16x8*)&WihT[col * 64 + s * 32 + kgrp * 8];
                acc = __builtin_amdgcn_mfma_f32_16x16x32_f16(ax[s], bx, acc, 0, 0, 0);
            }
            if (kgrp < 3) {       // rows t = kgrp*4+r < 12
                #pragma unroll
                for (int r = 0; r < 4; ++r)
                    xw[(kgrp * 4 + r) * 512 + col] = acc[r];
            }
        }
    }
    __syncthreads();

    // ---------- LSTM: 12 steps (validated r8/r9) ----------
    float cst = 0.f;
    for (int t = 0; t < L_; ++t) {
        f16x8 bf[4];
        #pragma unroll
        for (int s = 0; s < 4; ++s) {
            uint4 hb = *(const uint4*)&hpair[s * 16 + kgrp * 4];
            bf[s] = __builtin_bit_cast(f16x8, hb);
        }
        #pragma unroll
        for (int tt = 0; tt < 2; ++tt) {
            int colb = (2 * wv + tt) * 16 + kgrp * 4;
            f32x4 acc = *(const f32x4*)&xw[t * 512 + colb];
            #pragma unroll
            for (int s = 0; s < 4; ++s)
                acc = __builtin_amdgcn_mfma_f32_16x16x32_f16(af[tt][s], bf[s], acc, 0, 0, 0);
            if (m16 == 0) {
                part[colb + 0] = acc[0];
                part[colb + 1] = acc[1];
                part[colb + 2] = acc[2];
                part[colb + 3] = acc[3];
            }
        }
        __syncthreads();
        if (tid < R_) {
            float gi = part[tid], gf = part[R_ + tid], gg = part[2 * R_ + tid], go = part[3 * R_ + tid];
            cst = sigf(gf) * cst + sigf(gi) * tanhf(gg);
            float hn = sigf(go) * tanhf(cst);
            hbuf[tid] = hn;
            float hs = __shfl_down(hn, 1, 64);
            if (!(tid & 1)) hpair[tid >> 1] = pk16(hn, hs);
        }
        __syncthreads();
    }

    // ---------- stage Ws2P [64][132] via uint4 copy (xw dead) ----------
    {
        const uint4* src = (const uint4*)W2P;
        #pragma unroll
        for (int idx = tid; idx < 2048; idx += NT) {    // 2 iters
            uint4 v = src[idx];
            int jp = idx >> 5, kq = idx & 31;
            *(uint4*)&U[jp * 132 + kq * 4] = v;
        }
    }

    // ---------- P4: object MLP ----------
    {
        float acc = 0.f;
        int c0i = qq * 13, c1i = c0i + 13 < M2_ ? c0i + 13 : M2_;
        for (int c = c0i; c < c1i; ++c)
            acc += Wo1[(c * 32 + idx_o[c]) * R_ + k];
        part[qq * R_ + k] = acc;
    }
    __syncthreads();
    if (tid < R_) {
        float a = bo1[tid];
        #pragma unroll
        for (int q8 = 0; q8 < 8; ++q8) a += part[q8 * R_ + tid];
        tmp[tid] = fmaxf(a, 0.f);
    }
    __syncthreads();
    {
        float s0 = 0.f, s1 = 0.f, s2 = 0.f, s3 = 0.f;
        int j0 = qq * 16;
        #pragma unroll
        for (int j = 0; j < 16; j += 4) {
            s0 = fmaf(tmp[j0 + j + 0], Wo2[(j0 + j + 0) * R_ + k], s0);
            s1 = fmaf(tmp[j0 + j + 1], Wo2[(j0 + j + 1) * R_ + k], s1);
            s2 = fmaf(tmp[j0 + j + 2], Wo2[(j0 + j + 2) * R_ + k], s2);
            s3 = fmaf(tmp[j0 + j + 3], Wo2[(j0 + j + 3) * R_ + k], s3);
        }
        part[qq * R_ + k] = (s0 + s1) + (s2 + s3);
    }
    __syncthreads();
    if (tid < R_) {
        float a = bo2[tid];
        #pragma unroll
        for (int q8 = 0; q8 < 8; ++q8) a += part[q8 * R_ + tid];
        tmp2[tid] = fmaxf(a, 0.f);
    }
    __syncthreads();
    {
        float s0 = 0.f, s1 = 0.f, s2 = 0.f, s3 = 0.f;
        int j0 = qq * 16;
        #pragma unroll
        for (int j = 0; j < 16; j += 4) {
            s0 = fmaf(tmp2[j0 + j + 0], Wo3[(j0 + j + 0) * R_ + k], s0);
            s1 = fmaf(tmp2[j0 + j + 1], Wo3[(j0 + j + 1) * R_ + k], s1);
            s2 = fmaf(tmp2[j0 + j + 2], Wo3[(j0 + j + 2) * R_ + k], s2);
            s3 = fmaf(tmp2[j0 + j + 3], Wo3[(j0 + j + 3) * R_ + k], s3);
        }
        part[qq * R_ + k] = (s0 + s1) + (s2 + s3);
    }
    __syncthreads();
    if (tid < R_) {
        float a = bo3[tid];
        #pragma unroll
        for (int q8 = 0; q8 < 8; ++q8) a += part[q8 * R_ + tid];
        wbuf[tid] = a * hbuf[tid];
    }
    __syncthreads();

    // ---------- P5: u = Ws3 @ w ; c0 = bs3 . w ----------
    {
        float s0 = 0.f, s1 = 0.f, s2 = 0.f, s3 = 0.f;
        int j0 = qq * 16;
        const float4* w3 = reinterpret_cast<const float4*>(&Ws3[k * R_ + j0]);
        #pragma unroll
        for (int jj = 0; jj < 4; ++jj) {
            float4 v = w3[jj];
            s0 = fmaf(v.x, wbuf[j0 + jj * 4 + 0], s0);
            s1 = fmaf(v.y, wbuf[j0 + jj * 4 + 1], s1);
            s2 = fmaf(v.z, wbuf[j0 + jj * 4 + 2], s2);
            s3 = fmaf(v.w, wbuf[j0 + jj * 4 + 3], s3);
        }
        part[qq * R_ + k] = (s0 + s1) + (s2 + s3);
    }
    if (tid >= 960) {
        int j = tid - 960;
        float s = bs3[j] * wbuf[j] + bs3[j + 64] * wbuf[j + 64];
        s += __shfl_down(s, 32, 64);
        s += __shfl_down(s, 16, 64);
        s += __shfl_down(s, 8, 64);
        s += __shfl_down(s, 4, 64);
        s += __shfl_down(s, 2, 64);
        s += __shfl_down(s, 1, 64);
        if (j == 0) c0s = s;
    }
    __syncthreads();
    if (tid < R_) {
        float a = 0.f;
        #pragma unroll
        for (int q8 = 0; q8 < 8; ++q8) a += part[q8 * R_ + tid];
        ubuf[tid] = a;
    }
    __syncthreads();

    // ---------- P6: base_s gather ----------
    {
        float acc = 0.f;
        int c0i = qq * 13, c1i = c0i + 13 < M2_ ? c0i + 13 : M2_;
        for (int c = c0i; c < c1i; ++c)
            acc += Ws1[(c * 33 + idx_s[c]) * R_ + k];
        part[qq * R_ + k] = acc;
    }
    __syncthreads();
    if (tid < R_) {
        float a = bs1[tid];
        #pragma unroll
        for (int q8 = 0; q8 < 8; ++q8) a += part[q8 * R_ + tid];
        bsbuf[tid] = a;
    }
    __syncthreads();

    // ---------- stage h1P [112][68] f16-pairs; zero rows 100..111 ----------
    #pragma unroll 4
    for (int pass = 0; pass < 13; ++pass) {
        int idx = pass * NT + tid;
        if (idx < M2_ * R_) {
            int j = idx & 127, p = idx >> 7;
            float v = fmaxf(bsbuf[j] + Ws1[(p * 33 + 32) * R_ + j], 0.f);
            float v2 = __shfl_down(v, 1, 64);
            if (!(j & 1)) U[8448 + p * 68 + (j >> 1)] = pk16(v, v2);
        }
    }
    if (tid < 816) U[8448 + 6800 + tid] = 0u;
    __syncthreads();

    // ---------- P8: h2 = h1 @ Ws2 via MFMA; wave = (mtile, nhalf) ----------
    if (wv < 14) {
        const int mtile = wv >> 1, nhalf = wv & 1;
        const uint* Ap = U + 8448 + (mtile * 16 + m16) * 68;
        f16x8 A[4];
        #pragma unroll
        for (int s = 0; s < 4; ++s)
            A[s] = __builtin_bit_cast(f16x8, *(const uint4*)&Ap[s * 16 + kgrp * 4]);
        f32x4 acc[4] = { {0,0,0,0}, {0,0,0,0}, {0,0,0,0}, {0,0,0,0} };
        #pragma unroll
        for (int nt = 0; nt < 4; ++nt) {
            int ko = (nhalf * 4 + nt) * 16 + m16;
            #pragma unroll
            for (int s = 0; s < 4; ++s) {
                const uint* Bp = U + (s * 16 + kgrp * 4) * 132 + ko;
                uint4 bv = { Bp[0], Bp[132], Bp[264], Bp[396] };
                acc[nt] = __builtin_amdgcn_mfma_f32_16x16x32_f16(
                    A[s], __builtin_bit_cast(f16x8, bv), acc[nt], 0, 0, 0);
            }
        }
        float vs0 = 0.f, vs1 = 0.f, vs2 = 0.f, vs3 = 0.f;
        #pragma unroll
        for (int nt = 0; nt < 4; ++nt) {
            int ko = (nhalf * 4 + nt) * 16 + m16;
            float bb = bs2[ko], uu = ubuf[ko];
            vs0 = fmaf(fmaxf(acc[nt][0] + bb, 0.f), uu, vs0);
            vs1 = fmaf(fmaxf(acc[nt][1] + bb, 0.f), uu, vs1);
            vs2 = fmaf(fmaxf(acc[nt][2] + bb, 0.f), uu, vs2);
            vs3 = fmaf(fmaxf(acc[nt][3] + bb, 0.f), uu, vs3);
        }
        vs0 += __shfl_xor(vs0, 1, 64); vs0 += __shfl_xor(vs0, 2, 64);
        vs0 += __shfl_xor(vs0, 4, 64); vs0 += __shfl_xor(vs0, 8, 64);
        vs1 += __shfl_xor(vs1, 1, 64); vs1 += __shfl_xor(vs1, 2, 64);
        vs1 += __shfl_xor(vs1, 4, 64); vs1 += __shfl_xor(vs1, 8, 64);
        vs2 += __shfl_xor(vs2, 1, 64); vs2 += __shfl_xor(vs2, 2, 64);
        vs2 += __shfl_xor(vs2, 4, 64); vs2 += __shfl_xor(vs2, 8, 64);
        vs3 += __shfl_xor(vs3, 1, 64); vs3 += __shfl_xor(vs3, 2, 64);
        vs3 += __shfl_xor(vs3, 4, 64); vs3 += __shfl_xor(vs3, 8, 64);
        if (m16 == 0) {
            int pr = mtile * 16 + kgrp * 4;
            redw2[nhalf][pr + 0] = vs0;
            redw2[nhalf][pr + 1] = vs1;
            redw2[nhalf][pr + 2] = vs2;
            redw2[nhalf][pr + 3] = vs3;
        }
    }
    __syncthreads();

    // ---------- final ----------
    if (tid < M2_)
        out[b * M2_ + tid] = c0s + redw2[0][tid] + redw2[1][tid];
}

extern "C" void kernel_launch(void* const* d_in, const int* in_sizes, int n_in,
                              void* d_out, int out_size, void* d_ws, size_t ws_size,
                              hipStream_t stream) {
    const int*   state  = (const int*)d_in[0];
    const int*   obj    = (const int*)d_in[1];
    const int*   text   = (const int*)d_in[2];
    const float* Ws1    = (const float*)d_in[3];
    const float* bs1    = (const float*)d_in[4];
    const float* Ws2    = (const float*)d_in[5];
    const float* bs2    = (const float*)d_in[6];
    const float* Ws3    = (const float*)d_in[7];
    const float* bs3    = (const float*)d_in[8];
    const float* Wo1    = (const float*)d_in[9];
    const float* bo1    = (const float*)d_in[10];
    const float* Wo2    = (const float*)d_in[11];
    const float* bo2    = (const float*)d_in[12];
    const float* Wo3    = (const float*)d_in[13];
    const float* bo3    = (const float*)d_in[14];
    const float* emb    = (const float*)d_in[15];
    const float* Wih    = (const float*)d_in[16];
    const float* Whh    = (const float*)d_in[17];
    const float* b_lstm = (const float*)d_in[18];
    float* out = (float*)d_out;

    _Float16* WhhT = (_Float16*)d_ws;           // [512][128]
    _Float16* WihT = WhhT + 65536;              // [512][64]
    uint*     W2P  = (uint*)(WihT + 32768);     // [64][128]
    float*    sink = (float*)(W2P + 8192);      // touch sink (unused by main)

    hipLaunchKernelGGL(touch_kernel, dim3(512), dim3(256), 0, stream,
                       Wo1, Ws1, Wo2, Wo3, Ws3, emb, sink);
    hipLaunchKernelGGL(pack_kernel, dim3(416), dim3(256), 0, stream, Whh, Wih, Ws2, d_ws);
    hipLaunchKernelGGL(uvfa_kernel, dim3(B_), dim3(NT), 0, stream,
                       state, obj, text, Ws1, bs1, bs2, Ws3, bs3,
                       Wo1, bo1, Wo2, bo2, Wo3, bo3, emb, b_lstm,
                       WhhT, WihT, W2P, out);
}